// Round 1
// baseline (102.636 us; speedup 1.0000x reference)
//
#include <hip/hip_runtime.h>
#include <hip/hip_bf16.h>

#define KS   21
#define H    192
#define W    192
#define OH   172
#define OW   172
#define CROP 10
#define PLANE (H*W)

#define TXD  16
#define TYD  8
#define PXW  2                       // output pixels per thread (x)
#define TILE_W (TXD*PXW)             // 32
#define TILE_H (TYD)                 // 8
#define SROWS (TILE_H + KS - 1)      // 28
#define SCOLS (TILE_W + KS - 1)      // 52
#define WIN   (PXW + KS - 1)         // 22

__device__ __forceinline__ float softplusf_(float x) {
    // stable: max(x,0) + log(1 + exp(-|x|)); arg of log in (1,2] -> precise, no overflow
    float e = __expf(-fabsf(x));
    return fmaxf(x, 0.0f) + __logf(1.0f + e);
}

__global__ __launch_bounds__(TXD*TYD)
void adaptive_renderer_kernel(const float* __restrict__ kraw,
                              const float* __restrict__ rad,
                              const float* __restrict__ mask,
                              float* __restrict__ out)
{
    __shared__ float s_m [SROWS * SCOLS];
    __shared__ float s_r0[SROWS * SCOLS];
    __shared__ float s_r1[SROWS * SCOLS];
    __shared__ float s_r2[SROWS * SCOLS];

    const int b   = blockIdx.z;
    const int x0t = blockIdx.x * TILE_W;
    const int y0t = blockIdx.y * TILE_H;
    const int tx  = threadIdx.x, ty = threadIdx.y;
    const int tid = ty * TXD + tx;

    // ---- stage mask + radiance tile (clamped at image border; clamped
    // values are only read by threads whose outputs are out of range) ----
    const float* mbase = mask + (size_t)b * PLANE;
    const float* rbase = rad  + (size_t)b * 3 * PLANE;
    for (int t = tid; t < SROWS * SCOLS; t += TXD * TYD) {
        int rr = t / SCOLS, cc = t - rr * SCOLS;
        int gr = min(y0t + rr, H - 1);
        int gc = min(x0t + cc, W - 1);
        int off = gr * W + gc;
        s_m [t] = mbase[off];
        s_r0[t] = rbase[off];
        s_r1[t] = rbase[off + PLANE];
        s_r2[t] = rbase[off + 2 * PLANE];
    }
    __syncthreads();

    const int x0 = x0t + tx * PXW;   // first output x of this thread (even)
    const int y  = y0t + ty;

    // kernel_raw base for this thread; x0+CROP is even -> 8B-aligned float2.
    // Overshoot rows/cols stay inside the plane (max offset 185*192+201 < 36864),
    // results for OOB pixels are simply not stored.
    const float* kb = kraw + (size_t)b * KS * KS * PLANE
                           + (size_t)(y + CROP) * W + (x0 + CROP);

    float ks0 = 0.f, ks1 = 0.f;
    float a00 = 0.f, a01 = 0.f;
    float a10 = 0.f, a11 = 0.f;
    float a20 = 0.f, a21 = 0.f;

    #pragma unroll 1
    for (int i = 0; i < KS; ++i) {
        // sliding windows for this kernel row: cols [x0 .. x0+21] (block-local)
        float mw[WIN], r0w[WIN], r1w[WIN], r2w[WIN];
        const int ro = (ty + i) * SCOLS + tx * PXW;   // even -> float2-aligned
        #pragma unroll
        for (int m = 0; m < WIN / 2; ++m) {
            float2 v;
            v = *reinterpret_cast<const float2*>(&s_m [ro + 2*m]); mw [2*m] = v.x; mw [2*m+1] = v.y;
            v = *reinterpret_cast<const float2*>(&s_r0[ro + 2*m]); r0w[2*m] = v.x; r0w[2*m+1] = v.y;
            v = *reinterpret_cast<const float2*>(&s_r1[ro + 2*m]); r1w[2*m] = v.x; r1w[2*m+1] = v.y;
            v = *reinterpret_cast<const float2*>(&s_r2[ro + 2*m]); r2w[2*m] = v.x; r2w[2*m+1] = v.y;
        }
        const float* kp = kb + (size_t)i * KS * PLANE;
        #pragma unroll
        for (int j = 0; j < KS; ++j) {
            float2 kv = *reinterpret_cast<const float2*>(kp + (size_t)j * PLANE);
            float s0 = softplusf_(kv.x);
            float s1 = softplusf_(kv.y);
            float km0 = s0 * mw[j];
            float km1 = s1 * mw[j + 1];
            ks0 += km0;
            ks1 += km1;
            a00 = fmaf(km0, r0w[j],     a00);
            a01 = fmaf(km1, r0w[j + 1], a01);
            a10 = fmaf(km0, r1w[j],     a10);
            a11 = fmaf(km1, r1w[j + 1], a11);
            a20 = fmaf(km0, r2w[j],     a20);
            a21 = fmaf(km1, r2w[j + 1], a21);
        }
    }

    // ---- store: weighted_sum [4,3,172,172] then kernel_sum [4,1,172,172] ----
    if (y < OH) {
        const size_t cstride = (size_t)OH * OW;
        const size_t wbase = ((size_t)b * 3 * OH + y) * OW;
        const size_t kbase = (size_t)4 * 3 * OH * OW + ((size_t)b * OH + y) * OW;
        if (x0 < OW) {
            out[wbase + x0]               = a00;
            out[wbase + cstride + x0]     = a10;
            out[wbase + 2 * cstride + x0] = a20;
            out[kbase + x0]               = ks0;
        }
        if (x0 + 1 < OW) {
            out[wbase + x0 + 1]               = a01;
            out[wbase + cstride + x0 + 1]     = a11;
            out[wbase + 2 * cstride + x0 + 1] = a21;
            out[kbase + x0 + 1]               = ks1;
        }
    }
}

extern "C" void kernel_launch(void* const* d_in, const int* in_sizes, int n_in,
                              void* d_out, int out_size, void* d_ws, size_t ws_size,
                              hipStream_t stream) {
    const float* kraw = (const float*)d_in[0];   // [4,441,192,192] f32
    const float* rad  = (const float*)d_in[1];   // [4,3,192,192]   f32
    const float* mask = (const float*)d_in[2];   // [4,1,192,192]   f32
    float* out = (float*)d_out;                  // ws[4,3,172,172] ++ ks[4,1,172,172]

    dim3 block(TXD, TYD, 1);
    dim3 grid((OW + TILE_W - 1) / TILE_W, (OH + TILE_H - 1) / TILE_H, 4);
    hipLaunchKernelGGL(adaptive_renderer_kernel, grid, block, 0, stream,
                       kraw, rad, mask, out);
}

// Round 2
// 85.989 us; speedup vs baseline: 1.1936x; 1.1936x over previous
//
#include <hip/hip_runtime.h>
#include <hip/hip_bf16.h>

#define KS    21
#define H     192
#define W     192
#define OH    172
#define OW    172
#define CROP  10
#define PLANE (H*W)

#define NCHUNK 3
#define CROWS  7                       // kernel rows per chunk (3*7=21)

#define TXD   16
#define TYD   8
#define PXW   2
#define TILE_W 32
#define TILE_H 8
#define SROWS (TILE_H + CROWS - 1)     // 14
#define SCOLS (TILE_W + KS - 1)        // 52
#define SCH   (SCOLS / 2)              // 26 (per column-parity)

#define CS    (OH * OW)                // 29584
#define OUTN  (4 * 4 * OH * OW)        // one partial span = final out size = 473344

__device__ __forceinline__ float softplusf_(float x) {
    // stable: max(x,0) + log(1 + exp(-|x|))
    float e = __expf(-fabsf(x));
    return fmaxf(x, 0.0f) + __logf(1.0f + e);
}

__global__ __launch_bounds__(TXD * TYD)
void ar_partial_kernel(const float* __restrict__ kraw,
                       const float* __restrict__ rad,
                       const float* __restrict__ mask,
                       float* __restrict__ part)
{
    // {mask, r, g, b} packed per pixel, split by column parity so 16-lane
    // reads are stride-16B contiguous (standard conflict-free b128 pattern).
    __shared__ float4 s4[2][SROWS][SCH];

    const int zz    = blockIdx.z;          // grid.z = 12
    const int b     = zz & 3;
    const int chunk = zz >> 2;
    const int i0    = chunk * CROWS;

    const int x0t = blockIdx.x * TILE_W;
    const int y0t = blockIdx.y * TILE_H;
    const int tx  = threadIdx.x, ty = threadIdx.y;
    const int tid = ty * TXD + tx;

    // ---- stage mask + radiance for input rows [y0t+i0 .. y0t+i0+13] ----
    const float* mbase = mask + (size_t)b * PLANE;
    const float* rbase = rad  + (size_t)b * 3 * PLANE;
    for (int t = tid; t < SROWS * SCOLS; t += TXD * TYD) {
        int rr = t / SCOLS, cc = t - rr * SCOLS;
        int gr = min(y0t + i0 + rr, H - 1);    // clamped rows/cols only feed
        int gc = min(x0t + cc, W - 1);         // out-of-range outputs
        int off = gr * W + gc;
        float4 v;
        v.x = mbase[off];
        v.y = rbase[off];
        v.z = rbase[off + PLANE];
        v.w = rbase[off + 2 * PLANE];
        s4[cc & 1][rr][cc >> 1] = v;
    }
    __syncthreads();

    const int x0 = x0t + tx * PXW;             // even
    const int y  = y0t + ty;

    // all kraw accesses stay inside the [441][192][192] tensor even for
    // edge-overshoot threads (max tap 440, max in-plane offset < 36864)
    const float* kb = kraw + (size_t)b * KS * KS * PLANE
                           + (size_t)(y + CROP) * W + (x0 + CROP);

    float ks0 = 0.f, ks1 = 0.f;
    float a00 = 0.f, a01 = 0.f;
    float a10 = 0.f, a11 = 0.f;
    float a20 = 0.f, a21 = 0.f;

    #pragma unroll 1
    for (int i = 0; i < CROWS; ++i) {
        const float* kp = kb + (size_t)(i0 + i) * KS * PLANE;
        const int rr = ty + i;
        // rolling window: cur = pixel col (2tx + j), nxt = col (2tx + j + 1)
        float4 cur = s4[0][rr][tx];
        #pragma unroll
        for (int j = 0; j < KS; ++j) {
            float2 kv = *reinterpret_cast<const float2*>(kp + (size_t)j * PLANE);
            float4 nxt = s4[(j + 1) & 1][rr][tx + ((j + 1) >> 1)];
            float s0 = softplusf_(kv.x);
            float s1 = softplusf_(kv.y);
            float km0 = s0 * cur.x;
            float km1 = s1 * nxt.x;
            ks0 += km0;
            ks1 += km1;
            a00 = fmaf(km0, cur.y, a00);  a01 = fmaf(km1, nxt.y, a01);
            a10 = fmaf(km0, cur.z, a10);  a11 = fmaf(km1, nxt.z, a11);
            a20 = fmaf(km0, cur.w, a20);  a21 = fmaf(km1, nxt.w, a21);
            cur = nxt;
        }
    }

    // ---- store partial, layout mirroring final out, offset by chunk*OUTN ----
    if (y < OH && x0 < OW) {               // x0 even => x0+1 also valid
        float* pb = part + (size_t)chunk * OUTN;
        const size_t wbase = ((size_t)b * 3 * OH + y) * OW + x0;
        const size_t kbase = (size_t)12 * CS + ((size_t)b * OH + y) * OW + x0;
        *reinterpret_cast<float2*>(pb + wbase)          = make_float2(a00, a01);
        *reinterpret_cast<float2*>(pb + wbase + CS)     = make_float2(a10, a11);
        *reinterpret_cast<float2*>(pb + wbase + 2 * CS) = make_float2(a20, a21);
        *reinterpret_cast<float2*>(pb + kbase)          = make_float2(ks0, ks1);
    }
}

__global__ __launch_bounds__(256)
void ar_reduce_kernel(const float* __restrict__ part, float* __restrict__ out)
{
    int i = blockIdx.x * 256 + threadIdx.x;      // over OUTN/4 float4s
    if (i < OUTN / 4) {
        const float4* p4 = reinterpret_cast<const float4*>(part);
        float4 a = p4[i];
        float4 b = p4[i + OUTN / 4];
        float4 c = p4[i + 2 * (OUTN / 4)];
        float4 r;
        r.x = a.x + b.x + c.x;
        r.y = a.y + b.y + c.y;
        r.z = a.z + b.z + c.z;
        r.w = a.w + b.w + c.w;
        reinterpret_cast<float4*>(out)[i] = r;
    }
}

extern "C" void kernel_launch(void* const* d_in, const int* in_sizes, int n_in,
                              void* d_out, int out_size, void* d_ws, size_t ws_size,
                              hipStream_t stream) {
    const float* kraw = (const float*)d_in[0];   // [4,441,192,192] f32
    const float* rad  = (const float*)d_in[1];   // [4,3,192,192]   f32
    const float* mask = (const float*)d_in[2];   // [4,1,192,192]   f32
    float* out  = (float*)d_out;                 // ws[4,3,172,172] ++ ks[4,1,172,172]
    float* part = (float*)d_ws;                  // 3 partials of OUTN floats

    dim3 block(TXD, TYD, 1);
    dim3 grid((OW + TILE_W - 1) / TILE_W, (OH + TILE_H - 1) / TILE_H, 4 * NCHUNK);
    hipLaunchKernelGGL(ar_partial_kernel, grid, block, 0, stream,
                       kraw, rad, mask, part);

    int n4 = OUTN / 4;
    hipLaunchKernelGGL(ar_reduce_kernel, dim3((n4 + 255) / 256), dim3(256), 0, stream,
                       part, out);
}

// Round 3
// 77.707 us; speedup vs baseline: 1.3208x; 1.1066x over previous
//
#include <hip/hip_runtime.h>
#include <hip/hip_bf16.h>

#define KS    21
#define H     192
#define W     192
#define OH    172
#define OW    172
#define CROP  10
#define PLANE (H*W)

#define NCHUNK 7
#define CROWS  3                       // kernel rows per chunk (7*3=21)

#define TXD   16
#define TYD   8
#define PXW   2
#define TILE_W 32
#define TILE_H 8
#define SROWS (TILE_H + CROWS - 1)     // 10
#define SCOLS (TILE_W + KS - 1)        // 52
#define SCH   (SCOLS / 2)              // 26 (per column-parity)

#define CS    (OH * OW)                // 29584
#define OUTN  (4 * 4 * OH * OW)        // one partial span = final out size = 473344

__device__ __forceinline__ float softplusf_(float x) {
    // stable: max(x,0) + log(1 + exp(-|x|))
    float e = __expf(-fabsf(x));
    return fmaxf(x, 0.0f) + __logf(1.0f + e);
}

// issue one kraw row's 21 float2 loads into a static register array
#define LOADROW(buf, irow) do {                                              \
    const float* kp_ = kb + (size_t)(i0 + (irow)) * KS * PLANE;              \
    _Pragma("unroll")                                                        \
    for (int j = 0; j < KS; ++j)                                             \
        (buf)[j] = *reinterpret_cast<const float2*>(kp_ + (size_t)j * PLANE);\
} while (0)

// consume one row: softplus + mask + accumulate, rolling LDS window
#define COMPROW(buf, irow) do {                                              \
    const int rr_ = ty + (irow);                                             \
    float4 cur_ = s4[0][rr_][tx];                                            \
    _Pragma("unroll")                                                        \
    for (int j = 0; j < KS; ++j) {                                           \
        float4 nxt_ = s4[(j + 1) & 1][rr_][tx + ((j + 1) >> 1)];             \
        float s0_ = softplusf_((buf)[j].x);                                  \
        float s1_ = softplusf_((buf)[j].y);                                  \
        float km0_ = s0_ * cur_.x;                                           \
        float km1_ = s1_ * nxt_.x;                                           \
        ks0 += km0_;                                                         \
        ks1 += km1_;                                                         \
        a00 = fmaf(km0_, cur_.y, a00);  a01 = fmaf(km1_, nxt_.y, a01);       \
        a10 = fmaf(km0_, cur_.z, a10);  a11 = fmaf(km1_, nxt_.z, a11);       \
        a20 = fmaf(km0_, cur_.w, a20);  a21 = fmaf(km1_, nxt_.w, a21);       \
        cur_ = nxt_;                                                         \
    }                                                                        \
} while (0)

__global__ __launch_bounds__(TXD * TYD, 4)   // pin VGPR <=128 -> 4 waves/SIMD
void ar_partial_kernel(const float* __restrict__ kraw,
                       const float* __restrict__ rad,
                       const float* __restrict__ mask,
                       float* __restrict__ part)
{
    // {mask, r, g, b} packed per pixel, split by column parity so 16-lane
    // reads are stride-16B contiguous (conflict-free b128 pattern).
    __shared__ float4 s4[2][SROWS][SCH];

    const int zz    = blockIdx.z;          // grid.z = 4*NCHUNK = 28
    const int b     = zz & 3;
    const int chunk = zz >> 2;
    const int i0    = chunk * CROWS;

    const int x0t = blockIdx.x * TILE_W;
    const int y0t = blockIdx.y * TILE_H;
    const int tx  = threadIdx.x, ty = threadIdx.y;
    const int tid = ty * TXD + tx;

    // ---- stage mask + radiance for input rows [y0t+i0 .. y0t+i0+SROWS-1] ----
    const float* mbase = mask + (size_t)b * PLANE;
    const float* rbase = rad  + (size_t)b * 3 * PLANE;
    for (int t = tid; t < SROWS * SCOLS; t += TXD * TYD) {
        int rr = t / SCOLS, cc = t - rr * SCOLS;
        int gr = min(y0t + i0 + rr, H - 1);    // clamped rows/cols only feed
        int gc = min(x0t + cc, W - 1);         // out-of-range outputs
        int off = gr * W + gc;
        float4 v;
        v.x = mbase[off];
        v.y = rbase[off];
        v.z = rbase[off + PLANE];
        v.w = rbase[off + 2 * PLANE];
        s4[cc & 1][rr][cc >> 1] = v;
    }
    __syncthreads();

    const int x0 = x0t + tx * PXW;             // even
    const int y  = y0t + ty;

    // all kraw accesses stay inside the [441][192][192] tensor even for
    // edge-overshoot threads (max tap 440, max in-plane offset < 36864);
    // overshoot results are simply not stored.
    const float* kb = kraw + (size_t)b * KS * KS * PLANE
                           + (size_t)(y + CROP) * W + (x0 + CROP);

    float ks0 = 0.f, ks1 = 0.f;
    float a00 = 0.f, a01 = 0.f;
    float a10 = 0.f, a11 = 0.f;
    float a20 = 0.f, a21 = 0.f;

    // software-pipelined rows: keep up to 2 rows (42 loads, 21KB) in flight
    float2 kva[KS], kvb[KS];
    LOADROW(kva, 0);
    LOADROW(kvb, 1);
    COMPROW(kva, 0);
    LOADROW(kva, 2);
    COMPROW(kvb, 1);
    COMPROW(kva, 2);

    // ---- store partial, layout mirroring final out, offset by chunk*OUTN ----
    if (y < OH && x0 < OW) {               // x0 even => x0+1 also valid
        float* pb = part + (size_t)chunk * OUTN;
        const size_t wbase = ((size_t)b * 3 * OH + y) * OW + x0;
        const size_t kbase = (size_t)12 * CS + ((size_t)b * OH + y) * OW + x0;
        *reinterpret_cast<float2*>(pb + wbase)          = make_float2(a00, a01);
        *reinterpret_cast<float2*>(pb + wbase + CS)     = make_float2(a10, a11);
        *reinterpret_cast<float2*>(pb + wbase + 2 * CS) = make_float2(a20, a21);
        *reinterpret_cast<float2*>(pb + kbase)          = make_float2(ks0, ks1);
    }
}

__global__ __launch_bounds__(256)
void ar_reduce_kernel(const float* __restrict__ part, float* __restrict__ out)
{
    int i = blockIdx.x * 256 + threadIdx.x;      // over OUTN/4 float4s
    if (i < OUTN / 4) {
        const float4* p4 = reinterpret_cast<const float4*>(part);
        float4 r = p4[i];
        #pragma unroll
        for (int k = 1; k < NCHUNK; ++k) {
            float4 v = p4[i + (size_t)k * (OUTN / 4)];
            r.x += v.x; r.y += v.y; r.z += v.z; r.w += v.w;
        }
        reinterpret_cast<float4*>(out)[i] = r;
    }
}

extern "C" void kernel_launch(void* const* d_in, const int* in_sizes, int n_in,
                              void* d_out, int out_size, void* d_ws, size_t ws_size,
                              hipStream_t stream) {
    const float* kraw = (const float*)d_in[0];   // [4,441,192,192] f32
    const float* rad  = (const float*)d_in[1];   // [4,3,192,192]   f32
    const float* mask = (const float*)d_in[2];   // [4,1,192,192]   f32
    float* out  = (float*)d_out;                 // ws[4,3,172,172] ++ ks[4,1,172,172]
    float* part = (float*)d_ws;                  // NCHUNK partials of OUTN floats

    dim3 block(TXD, TYD, 1);
    dim3 grid((OW + TILE_W - 1) / TILE_W, (OH + TILE_H - 1) / TILE_H, 4 * NCHUNK);
    hipLaunchKernelGGL(ar_partial_kernel, grid, block, 0, stream,
                       kraw, rad, mask, part);

    int n4 = OUTN / 4;
    hipLaunchKernelGGL(ar_reduce_kernel, dim3((n4 + 255) / 256), dim3(256), 0, stream,
                       part, out);
}